// Round 2
// baseline (13.255 us; speedup 1.0000x reference)
//
#include <hip/hip_runtime.h>

// out[b,co,h,w] = max over ci of |x[b,ci,h,w] + w[co,ci]|
// B=8, CIN=COUT=64, H=W=56 -> HW=3136, spatial S = B*HW = 25088
//
// Decomposition: thread = (1 spatial, 4 co). Block = 256 threads (4 waves):
//   blockIdx = spatial-chunk (392) x co-quarter (4)  -> 1568 blocks, 6272 waves
//   lane -> spatial within 64-chunk (3136 % 64 == 0, so b is wave-uniform)
//   wave -> 4 consecutive co inside the block's 16-co quarter
// Inner loop: 2 ci per step, v_max3_f32 with abs() input modifiers fuses
// two |.|-maxes into one VOP3 instruction.

__global__ __launch_bounds__(256) void Conv1x1_53429393162852_kernel(
    const float* __restrict__ x, const float* __restrict__ w,
    float* __restrict__ out) {
  const int lane   = threadIdx.x & 63;
  const int wid    = threadIdx.x >> 6;          // 0..3
  const int schunk = blockIdx.x >> 2;           // 0..391 (co-quarter fastest:
  const int coq    = blockIdx.x & 3;            //  neighbors share the x-tile)
  const int s      = schunk * 64 + lane;        // spatial index < 25088
  const int b      = s / 3136;                  // wave-uniform
  const int hw     = s - b * 3136;
  // co base is wave-uniform -> SGPR -> weight reads become s_load.
  const int co0 = __builtin_amdgcn_readfirstlane(coq * 16 + wid * 4);

  const float* xp = x + (size_t)b * 64 * 3136 + hw;
  const float* wp = w + co0 * 64;

  float acc[4] = {0.0f, 0.0f, 0.0f, 0.0f};      // |.| >= 0: 0 is a safe floor

#pragma unroll
  for (int ci = 0; ci < 64; ci += 2) {
    const float xv0 = xp[(size_t)ci * 3136];
    const float xv1 = xp[(size_t)(ci + 1) * 3136];
#pragma unroll
    for (int j = 0; j < 4; ++j) {
      const float t0 = xv0 + wp[j * 64 + ci];       // v_add_f32 v, s, v
      const float t1 = xv1 + wp[j * 64 + ci + 1];
      // acc = max(acc, |t0|, |t1|) in ONE instruction (abs is a free VOP3
      // input modifier). Halves the max-chain instruction count.
      asm("v_max3_f32 %0, abs(%1), abs(%2), %0"
          : "+v"(acc[j]) : "v"(t0), "v"(t1));
    }
  }

  float* op = out + (size_t)b * 64 * 3136 + hw;
#pragma unroll
  for (int j = 0; j < 4; ++j) op[(size_t)(co0 + j) * 3136] = acc[j];
}

extern "C" void kernel_launch(void* const* d_in, const int* in_sizes, int n_in,
                              void* d_out, int out_size, void* d_ws, size_t ws_size,
                              hipStream_t stream) {
  const float* x = (const float*)d_in[0];      // (8, 64, 56, 56) fp32
  const float* w = (const float*)d_in[1];      // (64, 64, 1, 1)  fp32
  float* out = (float*)d_out;                  // (8, 64, 56, 56) fp32

  dim3 grid(392 * 4), block(256);
  hipLaunchKernelGGL(Conv1x1_53429393162852_kernel, grid, block, 0, stream,
                     x, w, out);
}